// Round 1
// 831.737 us; speedup vs baseline: 1.3592x; 1.3592x over previous
//
#include <hip/hip_runtime.h>
#include <cstddef>

static constexpr int HID = 1024;   // hidden
static constexpr int NB  = 4;      // batch
static constexpr int TT  = 2048;   // sequence (Ti == Tt)
static constexpr int UD  = 4096;   // conv units
static constexpr int PR  = TT + 1; // padded row stride (guard row per batch)

typedef short bf8    __attribute__((ext_vector_type(8)));  // 8 bf16 (4 VGPRs)
typedef float f32x4  __attribute__((ext_vector_type(4)));  // MFMA C/D frag

__device__ __forceinline__ unsigned short f2bf(float x) {
  unsigned int u = __float_as_uint(x);
  u += 0x7fffu + ((u >> 16) & 1u);          // round-to-nearest-even
  return (unsigned short)(u >> 16);
}
__device__ __forceinline__ float bf2f(unsigned short h) {
  return __uint_as_float(((unsigned int)h) << 16);
}
__device__ __forceinline__ unsigned short cvt_bf(float x) { return f2bf(x); }
__device__ __forceinline__ unsigned short cvt_bf(unsigned short x) { return x; }

// async global->LDS, 16B per lane. LDS dest must be wave-uniform base + lane*16
// (m104/m108) — all staging below satisfies this by construction (dest = base + tid*16B).
__device__ __forceinline__ void g2l16(const unsigned short* g, unsigned short* l) {
  __builtin_amdgcn_global_load_lds(
      (const __attribute__((address_space(1))) unsigned int*)g,
      (__attribute__((address_space(3))) unsigned int*)l, 16, 0, 0);
}

#define BARX() __builtin_amdgcn_s_barrier()
#define VMCNT(n) asm volatile("s_waitcnt vmcnt(" #n ")" ::: "memory")

// ---- gather row + scale, split into bf16 hi/lo:  hi+lo ~= scale*emb[idx] ----
__global__ __launch_bounds__(256) void gather_split_k(
    const int* __restrict__ idx, const float* __restrict__ emb,
    unsigned short* __restrict__ hi, unsigned short* __restrict__ lo, float scale)
{
  const int row = blockIdx.x;
  const int r = idx[row];
  const int c = threadIdx.x * 4;
  float4 v = *(const float4*)(emb + (size_t)r * HID + c);
  v.x *= scale; v.y *= scale; v.z *= scale; v.w *= scale;
  ushort4 h, l;
  h.x = f2bf(v.x); h.y = f2bf(v.y); h.z = f2bf(v.z); h.w = f2bf(v.w);
  l.x = f2bf(v.x - bf2f(h.x)); l.y = f2bf(v.y - bf2f(h.y));
  l.z = f2bf(v.z - bf2f(h.z)); l.w = f2bf(v.w - bf2f(h.w));
  *(ushort4*)(hi + (size_t)row * HID + c) = h;
  *(ushort4*)(lo + (size_t)row * HID + c) = l;
}

// ---- zero the 5 guard rows of the padded attn buffer ----------------------
__global__ __launch_bounds__(256) void zero_guard_k(unsigned short* __restrict__ p)
{
  unsigned short* row = p + (size_t)blockIdx.x * PR * HID;
  *(ushort4*)(row + threadIdx.x * 4) = (ushort4){0, 0, 0, 0};
}

// ---- generic transpose to bf16: out[c][r] = bf16(in[r][c]) ----------------
template<typename TIN>
__global__ __launch_bounds__(256) void transpose_bf_k(
    const TIN* __restrict__ in, unsigned short* __restrict__ out,
    int R, int C, long long sIn, long long sOut)
{
  __shared__ unsigned short tile[32][33];
  in  += (size_t)blockIdx.z * sIn;
  out += (size_t)blockIdx.z * sOut;
  const int r0 = blockIdx.y * 32, c0 = blockIdx.x * 32;
  const int tc = threadIdx.x & 31, tr8 = threadIdx.x >> 5;
#pragma unroll
  for (int p = 0; p < 4; ++p) {
    const int r = tr8 + p * 8;
    tile[r][tc] = cvt_bf(in[(size_t)(r0 + r) * C + c0 + tc]);
  }
  __syncthreads();
#pragma unroll
  for (int p = 0; p < 4; ++p) {
    const int c = tr8 + p * 8;
    out[(size_t)(c0 + c) * R + r0 + tc] = tile[tc][c];
  }
}

// ---- row softmax over TT cols: fp32 in -> bf16 out ------------------------
__global__ __launch_bounds__(256) void softmax_bf_k(
    const float* __restrict__ L, unsigned short* __restrict__ W)
{
  const float* row = L + (size_t)blockIdx.x * TT;
  unsigned short* wout = W + (size_t)blockIdx.x * TT;
  const int tid = threadIdx.x;
  float4 v0 = ((const float4*)row)[tid * 2];
  float4 v1 = ((const float4*)row)[tid * 2 + 1];
  float mx = fmaxf(fmaxf(fmaxf(v0.x, v0.y), fmaxf(v0.z, v0.w)),
                   fmaxf(fmaxf(v1.x, v1.y), fmaxf(v1.z, v1.w)));
#pragma unroll
  for (int off = 32; off > 0; off >>= 1)
    mx = fmaxf(mx, __shfl_xor(mx, off, 64));
  __shared__ float sred[8];
  const int wid = tid >> 6;
  if ((tid & 63) == 0) sred[wid] = mx;
  __syncthreads();
  mx = fmaxf(fmaxf(sred[0], sred[1]), fmaxf(sred[2], sred[3]));
  v0.x = __expf(v0.x - mx); v0.y = __expf(v0.y - mx);
  v0.z = __expf(v0.z - mx); v0.w = __expf(v0.w - mx);
  v1.x = __expf(v1.x - mx); v1.y = __expf(v1.y - mx);
  v1.z = __expf(v1.z - mx); v1.w = __expf(v1.w - mx);
  float s = v0.x + v0.y + v0.z + v0.w + v1.x + v1.y + v1.z + v1.w;
#pragma unroll
  for (int off = 32; off > 0; off >>= 1)
    s += __shfl_xor(s, off, 64);
  if ((tid & 63) == 0) sred[4 + wid] = s;
  __syncthreads();
  s = sred[4] + sred[5] + sred[6] + sred[7];
  const float inv = 1.0f / s;
  ushort4 o0, o1;
  o0.x = f2bf(v0.x * inv); o0.y = f2bf(v0.y * inv);
  o0.z = f2bf(v0.z * inv); o0.w = f2bf(v0.w * inv);
  o1.x = f2bf(v1.x * inv); o1.y = f2bf(v1.y * inv);
  o1.z = f2bf(v1.z * inv); o1.w = f2bf(v1.w * inv);
  *(ushort4*)(wout + tid * 8)     = o0;
  *(ushort4*)(wout + tid * 8 + 4) = o1;
}

// ===========================================================================
// 256x256 / BK=64 / 8-wave / 4-phase-per-K-tile bf16 GEMM (T2+T3+T4+T5).
// C[M][N] = A[M][K] . B[N][K]^T.
//
// LDS: As/Bs[buf][ks-half][256 rows][32 k] bf16, 2 buffers = 128 KiB total.
// Swizzle (T2): LDS k-byte = data k-byte ^ (((row>>1)&3)<<4). Involution,
//   16B-granular, within-row. Applied on the *global source* address during
//   global_load_lds staging (LDS dest stays linear, m104), and on the
//   ds_read address. Read conflict drops 8-way -> 2-way (free, m136).
// Schedule (T3/T4): per K-tile t, 4 phases; phase p stages one (matrix,ks)
//   half of tile t+1 (2 x g2l16/thread). ks0 halves of t+1 staged at p0/p1,
//   ks1 at p2/p3. vmcnt(4) at p1-end guards tile t's ks1 (read at p2/p3);
//   vmcnt(4) at p3-end guards tile t+1's ks0 (read at next p0/p1). Raw
//   s_barrier (no vmcnt(0) drain) elsewhere; final tile drains with vmcnt(0).
//   Write-after-read safe: tile t+1 staging (issued >= tile-t p0) lands after
//   tile t-1's last reads (done before the p3(t-1) barrier).
// T5: setprio(1) around each 16-MFMA cluster.
// ===========================================================================
template<int CONVA>
__device__ __forceinline__ void stage_half(
    const unsigned short* __restrict__ P, int ld, int r0, int t, int ks,
    unsigned short* lds, int tid)
{
  const int bk = t * 64 + ks * 32;
  // pre-swizzled source k-offset: ke = ((tid&3) ^ ((tid>>3)&3)) * 8 elems
  const int ke = (((tid & 3) ^ ((tid >> 3) & 3)) << 3);
  int rowbase, kcol;
  if constexpr (CONVA) {
    const int seg = bk >> 10;                 // block-uniform (8|ke, 32|bk)
    kcol = (bk & 1023) + ke;
    rowbase = r0 + (tid >> 2) + seg - 1;      // guard rows absorb -1/+2
  } else {
    kcol = bk + ke;
    rowbase = r0 + (tid >> 2);
  }
#pragma unroll
  for (int c = 0; c < 2; ++c)
    g2l16(P + (ptrdiff_t)(rowbase + c * 128) * ld + kcol,
          lds + c * 4096 + tid * 8);
}

template<int OUTBF, int EPI, int CONVA>
__global__ __launch_bounds__(512, 2) void gemm256_k(
    const unsigned short* __restrict__ A, long long sA, int lda,
    const unsigned short* __restrict__ B, long long sB, int ldb,
    void* __restrict__ Cv, long long sC, int ldc,
    int K, const float* __restrict__ bias)
{
  __shared__ __align__(16) unsigned short As[2][2][256 * 32];
  __shared__ __align__(16) unsigned short Bs[2][2][256 * 32];
  const int tid = threadIdx.x;
  A += (size_t)blockIdx.z * sA;
  B += (size_t)blockIdx.z * sB;
  const int bm = blockIdx.y * 256;
  const int bn = blockIdx.x * 256;
  const int wave = tid >> 6, lane = tid & 63;
  const int wr = wave >> 2, wcn = wave & 3;   // 2x4 wave grid, 128x64 C/wave
  const int q = lane >> 4, l16 = lane & 15;
  const int ksw = ((q ^ ((l16 >> 1) & 3)) << 3);       // swizzled k-read off
  const int abase = (wr * 128 + l16) * 32 + ksw;
  const int bbase = (wcn * 64 + l16) * 32 + ksw;

  f32x4 acc[8][4];
#pragma unroll
  for (int i = 0; i < 8; ++i)
#pragma unroll
    for (int j = 0; j < 4; ++j)
      acc[i][j] = (f32x4){0.f, 0.f, 0.f, 0.f};

  const int T = K >> 6;

  // prologue: tile 0 fully staged; wait for its ks0 (oldest 4 loads)
  stage_half<CONVA>(A, lda, bm, 0, 0, &As[0][0][0], tid);
  stage_half<0>   (B, ldb, bn, 0, 0, &Bs[0][0][0], tid);
  stage_half<CONVA>(A, lda, bm, 0, 1, &As[0][1][0], tid);
  stage_half<0>   (B, ldb, bn, 0, 1, &Bs[0][1][0], tid);
  VMCNT(4);
  BARX();

  bf8 af[4], bfr[4];
  for (int t = 0; t < T; ++t) {
    const int buf = t & 1;
    unsigned short* An0 = &As[buf ^ 1][0][0];
    unsigned short* An1 = &As[buf ^ 1][1][0];
    unsigned short* Bn0 = &Bs[buf ^ 1][0][0];
    unsigned short* Bn1 = &Bs[buf ^ 1][1][0];
    const bool next = (t + 1 < T);

    // ---- phase 0: ks0, i 0..3 ----
#pragma unroll
    for (int j = 0; j < 4; ++j) bfr[j] = *(const bf8*)&Bs[buf][0][bbase + j * 512];
#pragma unroll
    for (int m = 0; m < 4; ++m) af[m] = *(const bf8*)&As[buf][0][abase + m * 512];
    if (next) stage_half<CONVA>(A, lda, bm, t + 1, 0, An0, tid);
    BARX();
    __builtin_amdgcn_s_setprio(1);
#pragma unroll
    for (int m = 0; m < 4; ++m)
#pragma unroll
      for (int j = 0; j < 4; ++j)
        acc[m][j] = __builtin_amdgcn_mfma_f32_16x16x32_bf16(af[m], bfr[j], acc[m][j], 0, 0, 0);
    __builtin_amdgcn_s_setprio(0);
    BARX();

    // ---- phase 1: ks0, i 4..7 ----
#pragma unroll
    for (int m = 0; m < 4; ++m) af[m] = *(const bf8*)&As[buf][0][abase + (4 + m) * 512];
    if (next) { stage_half<0>(B, ldb, bn, t + 1, 0, Bn0, tid); VMCNT(4); }
    else      { VMCNT(0); }
    BARX();
    __builtin_amdgcn_s_setprio(1);
#pragma unroll
    for (int m = 0; m < 4; ++m)
#pragma unroll
      for (int j = 0; j < 4; ++j)
        acc[4 + m][j] = __builtin_amdgcn_mfma_f32_16x16x32_bf16(af[m], bfr[j], acc[4 + m][j], 0, 0, 0);
    __builtin_amdgcn_s_setprio(0);
    BARX();

    // ---- phase 2: ks1, i 0..3 ----
#pragma unroll
    for (int j = 0; j < 4; ++j) bfr[j] = *(const bf8*)&Bs[buf][1][bbase + j * 512];
#pragma unroll
    for (int m = 0; m < 4; ++m) af[m] = *(const bf8*)&As[buf][1][abase + m * 512];
    if (next) stage_half<CONVA>(A, lda, bm, t + 1, 1, An1, tid);
    BARX();
    __builtin_amdgcn_s_setprio(1);
#pragma unroll
    for (int m = 0; m < 4; ++m)
#pragma unroll
      for (int j = 0; j < 4; ++j)
        acc[m][j] = __builtin_amdgcn_mfma_f32_16x16x32_bf16(af[m], bfr[j], acc[m][j], 0, 0, 0);
    __builtin_amdgcn_s_setprio(0);
    BARX();

    // ---- phase 3: ks1, i 4..7 ----
#pragma unroll
    for (int m = 0; m < 4; ++m) af[m] = *(const bf8*)&As[buf][1][abase + (4 + m) * 512];
    if (next) { stage_half<0>(B, ldb, bn, t + 1, 1, Bn1, tid); VMCNT(4); }
    BARX();
    __builtin_amdgcn_s_setprio(1);
#pragma unroll
    for (int m = 0; m < 4; ++m)
#pragma unroll
      for (int j = 0; j < 4; ++j)
        acc[4 + m][j] = __builtin_amdgcn_mfma_f32_16x16x32_bf16(af[m], bfr[j], acc[4 + m][j], 0, 0, 0);
    __builtin_amdgcn_s_setprio(0);
    BARX();
  }

  // ---- epilogue -----------------------------------------------------------
  float* Cf          = (float*)Cv          + (size_t)blockIdx.z * sC;
  unsigned short* Cb = (unsigned short*)Cv + (size_t)blockIdx.z * sC;
#pragma unroll
  for (int j = 0; j < 4; ++j) {
    const int col = bn + wcn * 64 + j * 16 + l16;
    float bv = 0.f;
    if constexpr (EPI >= 1) bv = bias[col];
#pragma unroll
    for (int i = 0; i < 8; ++i) {
      const int row0 = bm + wr * 128 + i * 16 + q * 4;
#pragma unroll
      for (int r = 0; r < 4; ++r) {
        float v = acc[i][j][r];
        if constexpr (EPI >= 1) v += bv;
        if constexpr (EPI == 2) v = fmaxf(v, 0.f);
        if constexpr (OUTBF) Cb[(size_t)(row0 + r) * ldc + col] = f2bf(v);
        else                 Cf[(size_t)(row0 + r) * ldc + col] = v;
      }
    }
  }
}

// ---- fused hi/lo logits GEMM: C = Ah.Bh^T + Ah.Bl^T + Al.Bh^T (fp32 C) ----
// Fixed shapes: lda=ldb=HID, M=N=TT, K=HID, ldc=TT.  (unchanged this round)
__global__ __launch_bounds__(256) void gemm_logits_k(
    const unsigned short* __restrict__ Ah, const unsigned short* __restrict__ Al,
    const unsigned short* __restrict__ Bh, const unsigned short* __restrict__ Bl,
    float* __restrict__ C)
{
  __shared__ unsigned short AsH[4 * 128 * 8], AsL[4 * 128 * 8];
  __shared__ unsigned short BsH[4 * 128 * 8], BsL[4 * 128 * 8];
  const int tid = threadIdx.x;
  const long long SE = (long long)TT * HID;
  Ah += (size_t)blockIdx.z * SE; Al += (size_t)blockIdx.z * SE;
  Bh += (size_t)blockIdx.z * SE; Bl += (size_t)blockIdx.z * SE;
  C  += (size_t)blockIdx.z * TT * TT;
  const int bm = blockIdx.y * 128;
  const int bn = blockIdx.x * 128;
  const int wave = tid >> 6, lane = tid & 63;
  const int wr = wave >> 1, wc = wave & 1;
  const int q = lane >> 4, l16 = lane & 15;
  const int sr  = tid & 127;
  const int skb = tid >> 7;

  f32x4 acc[4][4];
#pragma unroll
  for (int i = 0; i < 4; ++i)
#pragma unroll
    for (int j = 0; j < 4; ++j)
      acc[i][j] = (f32x4){0.f, 0.f, 0.f, 0.f};

  for (int k0 = 0; k0 < HID; k0 += 32) {
#pragma unroll
    for (int h = 0; h < 2; ++h) {
      const int kb = skb + h * 2;
      const int kk = k0 + kb * 8;
      const size_t ao = (size_t)(bm + sr) * HID + kk;
      const size_t bo = (size_t)(bn + sr) * HID + kk;
      const int lo = (kb * 128 + sr) * 8;
      g2l16(Ah + ao, &AsH[lo]);
      g2l16(Al + ao, &AsL[lo]);
      g2l16(Bh + bo, &BsH[lo]);
      g2l16(Bl + bo, &BsL[lo]);
    }
    __syncthreads();
    bf8 ah[4], al[4], bh[4], bl[4];
#pragma unroll
    for (int i = 0; i < 4; ++i) {
      const int lo = (q * 128 + wr * 64 + i * 16 + l16) * 8;
      ah[i] = *(const bf8*)&AsH[lo];
      al[i] = *(const bf8*)&AsL[lo];
    }
#pragma unroll
    for (int j = 0; j < 4; ++j) {
      const int lo = (q * 128 + wc * 64 + j * 16 + l16) * 8;
      bh[j] = *(const bf8*)&BsH[lo];
      bl[j] = *(const bf8*)&BsL[lo];
    }
#pragma unroll
    for (int i = 0; i < 4; ++i)
#pragma unroll
      for (int j = 0; j < 4; ++j) {
        acc[i][j] = __builtin_amdgcn_mfma_f32_16x16x32_bf16(ah[i], bh[j], acc[i][j], 0, 0, 0);
        acc[i][j] = __builtin_amdgcn_mfma_f32_16x16x32_bf16(ah[i], bl[j], acc[i][j], 0, 0, 0);
        acc[i][j] = __builtin_amdgcn_mfma_f32_16x16x32_bf16(al[i], bh[j], acc[i][j], 0, 0, 0);
      }
    __syncthreads();
  }

#pragma unroll
  for (int j = 0; j < 4; ++j) {
    const int col = bn + wc * 64 + j * 16 + l16;
#pragma unroll
    for (int i = 0; i < 4; ++i) {
      const int row0 = bm + wr * 64 + i * 16 + q * 4;
#pragma unroll
      for (int r = 0; r < 4; ++r)
        C[(size_t)(row0 + r) * TT + col] = acc[i][j][r];
    }
  }
}

extern "C" void kernel_launch(void* const* d_in, const int* in_sizes, int n_in,
                              void* d_out, int out_size, void* d_ws, size_t ws_size,
                              hipStream_t stream)
{
  const int*   inputs     = (const int*)d_in[0];
  const int*   targets    = (const int*)d_in[1];
  const float* input_emb  = (const float*)d_in[2];
  const float* target_emb = (const float*)d_in[3];
  const float* conv_w     = (const float*)d_in[4];
  const float* conv_b     = (const float*)d_in[5];
  const float* dense_w    = (const float*)d_in[6];
  const float* dense_b    = (const float*)d_in[7];
  float* out = (float*)d_out;

  const long long SE = (long long)TT * HID;     // elems per batch (te/ie)
  const size_t SZ = (size_t)NB * SE * 2;        // 16,777,216 B bf16 region

  // workspace map (167,772,160 B total, proven capacity):
  // [0,SZ)        te_hi          -> ieT after logits
  // [SZ,..)       te_lo          -> attn padded (NB*PR+1 rows = 16,787,456 B)
  // [2SZ,3SZ)     ie_hi          -> convwb @ 2SZ+16K (25.2 MB, spans ie_lo)
  // [3SZ,4SZ)     ie_lo
  // [4SZ,4SZ+67M) logit fp32     -> hb bf16 after softmax
  // [4SZ+67M,end) Wbf bf16       -> densewb after attn GEMM
  char* base = (char*)d_ws;
  unsigned short* te_hi = (unsigned short*)(base);
  unsigned short* te_lo = (unsigned short*)(base + SZ);
  unsigned short* ie_hi = (unsigned short*)(base + 2 * SZ);
  unsigned short* ie_lo = (unsigned short*)(base + 3 * SZ);
  float*          logit = (float*)         (base + 4 * SZ);
  unsigned short* Wbf   = (unsigned short*)(base + 4 * SZ + (size_t)NB * TT * TT * 4);
  unsigned short* ieT     = (unsigned short*)(base);
  unsigned short* attnP   = (unsigned short*)(base + SZ);              // padded buffer base
  unsigned short* attnD   = attnP + (size_t)HID;                       // first data row
  unsigned short* convwb  = (unsigned short*)(base + 2 * SZ + 16384);
  unsigned short* hb      = (unsigned short*)(base + 4 * SZ);
  unsigned short* densewb = (unsigned short*)Wbf;

  // 1) gathers: te raw, ie scaled by sqrt(H)=32  (logits = te_raw . ie_scaled)
  gather_split_k<<<NB * TT, 256, 0, stream>>>(targets, target_emb, te_hi, te_lo, 1.0f);
  gather_split_k<<<NB * TT, 256, 0, stream>>>(inputs,  input_emb,  ie_hi, ie_lo, 32.0f);

  // 2) fused hi/lo logits
  gemm_logits_k<<<dim3(TT / 128, TT / 128, NB), 256, 0, stream>>>(
      te_hi, te_lo, ie_hi, ie_lo, logit);

  // 3) ieT[h][s] = ie_hi[s][h]  (overwrites te_hi, dead)
  transpose_bf_k<unsigned short><<<dim3(HID / 32, TT / 32, NB), 256, 0, stream>>>(
      ie_hi, ieT, TT, HID, SE, SE);

  // 4) softmax -> bf16 W
  softmax_bf_k<<<NB * TT, 256, 0, stream>>>(logit, Wbf);

  // 5) guard rows + attn[t][h] = W[t][s] . ieT[h][s] -> padded bf16 buffer
  zero_guard_k<<<NB + 1, 256, 0, stream>>>(attnP);
  gemm256_k<1, 0, 0><<<dim3(HID / 256, TT / 256, NB), 512, 0, stream>>>(
      Wbf, (long long)TT * TT, TT, ieT, SE, TT,
      attnD, (long long)PR * HID, HID, TT, nullptr);

  // 6) weight transposes (convwb over dead ie region; densewb over dead Wbf)
  transpose_bf_k<float><<<dim3(UD / 32, (3 * HID) / 32, 1), 256, 0, stream>>>(
      conv_w, convwb, 3 * HID, UD, 0, 0);
  transpose_bf_k<float><<<dim3(HID / 32, UD / 32, 1), 256, 0, stream>>>(
      dense_w, densewb, UD, HID, 0, 0);

  // 7) conv: h = relu(b + im2col(attn).convwb^T) -> bf16 (over dead logit)
  gemm256_k<1, 2, 1><<<dim3(UD / 256, TT / 256, NB), 512, 0, stream>>>(
      attnD, (long long)PR * HID, HID, convwb, 0, 3 * HID,
      hb, (long long)TT * UD, UD, 3 * HID, conv_b);

  // 8) dense: out = b + h.densewb^T  (fp32 out)
  gemm256_k<0, 1, 0><<<dim3(HID / 256, TT / 256, NB), 512, 0, stream>>>(
      hb, (long long)TT * UD, UD, densewb, 0, UD,
      out, SE, HID, UD, dense_b);
}

// Round 2
// 724.518 us; speedup vs baseline: 1.5604x; 1.1480x over previous
//
#include <hip/hip_runtime.h>
#include <cstddef>

static constexpr int HID = 1024;   // hidden
static constexpr int NB  = 4;      // batch
static constexpr int TT  = 2048;   // sequence (Ti == Tt)
static constexpr int UD  = 4096;   // conv units
static constexpr int PR  = TT + 1; // padded row stride (guard row per batch)

typedef short bf8    __attribute__((ext_vector_type(8)));  // 8 bf16 (4 VGPRs)
typedef float f32x4  __attribute__((ext_vector_type(4)));  // MFMA C/D frag

__device__ __forceinline__ unsigned short f2bf(float x) {
  unsigned int u = __float_as_uint(x);
  u += 0x7fffu + ((u >> 16) & 1u);          // round-to-nearest-even
  return (unsigned short)(u >> 16);
}
__device__ __forceinline__ float bf2f(unsigned short h) {
  return __uint_as_float(((unsigned int)h) << 16);
}
__device__ __forceinline__ unsigned short cvt_bf(float x) { return f2bf(x); }
__device__ __forceinline__ unsigned short cvt_bf(unsigned short x) { return x; }

// async global->LDS, 16B per lane. LDS dest must be wave-uniform base + lane*16
// (m104/m108) — all staging below satisfies this by construction.
__device__ __forceinline__ void g2l16(const unsigned short* g, unsigned short* l) {
  __builtin_amdgcn_global_load_lds(
      (const __attribute__((address_space(1))) unsigned int*)g,
      (__attribute__((address_space(3))) unsigned int*)l, 16, 0, 0);
}

#define BARX() __builtin_amdgcn_s_barrier()
#define VMCNT(n) asm volatile("s_waitcnt vmcnt(" #n ")" ::: "memory")

// T1: bijective XCD-chunked block swizzle (requires nwg % 8 == 0 — all our
// MFMA grids are 128/256/512). Maps hardware round-robin XCD assignment to
// contiguous chunks of the logical grid for L2 A/B-panel reuse.
__device__ __forceinline__ void xcd_swz(int& bx, int& by, int& bz) {
  const int gx = gridDim.x, gy = gridDim.y;
  const int nwg = gx * gy * (int)gridDim.z;
  int flat = bx + gx * (by + gy * bz);
  const int cpx = nwg >> 3;
  flat = (flat & 7) * cpx + (flat >> 3);
  bx = flat % gx; flat /= gx;
  by = flat % gy; bz = flat / gy;
}

// ---- gather row + scale, split into bf16 hi/lo:  hi+lo ~= scale*emb[idx] ----
__global__ __launch_bounds__(256) void gather_split_k(
    const int* __restrict__ idx, const float* __restrict__ emb,
    unsigned short* __restrict__ hi, unsigned short* __restrict__ lo, float scale)
{
  const int row = blockIdx.x;
  const int r = idx[row];
  const int c = threadIdx.x * 4;
  float4 v = *(const float4*)(emb + (size_t)r * HID + c);
  v.x *= scale; v.y *= scale; v.z *= scale; v.w *= scale;
  ushort4 h, l;
  h.x = f2bf(v.x); h.y = f2bf(v.y); h.z = f2bf(v.z); h.w = f2bf(v.w);
  l.x = f2bf(v.x - bf2f(h.x)); l.y = f2bf(v.y - bf2f(h.y));
  l.z = f2bf(v.z - bf2f(h.z)); l.w = f2bf(v.w - bf2f(h.w));
  *(ushort4*)(hi + (size_t)row * HID + c) = h;
  *(ushort4*)(lo + (size_t)row * HID + c) = l;
}

// ---- zero the 5 guard rows of the padded attn buffer ----------------------
__global__ __launch_bounds__(256) void zero_guard_k(unsigned short* __restrict__ p)
{
  unsigned short* row = p + (size_t)blockIdx.x * PR * HID;
  *(ushort4*)(row + threadIdx.x * 4) = (ushort4){0, 0, 0, 0};
}

// ---- generic transpose to bf16: out[c][r] = bf16(in[r][c]) ----------------
template<typename TIN>
__global__ __launch_bounds__(256) void transpose_bf_k(
    const TIN* __restrict__ in, unsigned short* __restrict__ out,
    int R, int C, long long sIn, long long sOut)
{
  __shared__ unsigned short tile[32][33];
  in  += (size_t)blockIdx.z * sIn;
  out += (size_t)blockIdx.z * sOut;
  const int r0 = blockIdx.y * 32, c0 = blockIdx.x * 32;
  const int tc = threadIdx.x & 31, tr8 = threadIdx.x >> 5;
#pragma unroll
  for (int p = 0; p < 4; ++p) {
    const int r = tr8 + p * 8;
    tile[r][tc] = cvt_bf(in[(size_t)(r0 + r) * C + c0 + tc]);
  }
  __syncthreads();
#pragma unroll
  for (int p = 0; p < 4; ++p) {
    const int c = tr8 + p * 8;
    out[(size_t)(c0 + c) * R + r0 + tc] = tile[tc][c];
  }
}

// ---- row softmax over TT cols: fp32 in -> bf16 out ------------------------
__global__ __launch_bounds__(256) void softmax_bf_k(
    const float* __restrict__ L, unsigned short* __restrict__ W)
{
  const float* row = L + (size_t)blockIdx.x * TT;
  unsigned short* wout = W + (size_t)blockIdx.x * TT;
  const int tid = threadIdx.x;
  float4 v0 = ((const float4*)row)[tid * 2];
  float4 v1 = ((const float4*)row)[tid * 2 + 1];
  float mx = fmaxf(fmaxf(fmaxf(v0.x, v0.y), fmaxf(v0.z, v0.w)),
                   fmaxf(fmaxf(v1.x, v1.y), fmaxf(v1.z, v1.w)));
#pragma unroll
  for (int off = 32; off > 0; off >>= 1)
    mx = fmaxf(mx, __shfl_xor(mx, off, 64));
  __shared__ float sred[8];
  const int wid = tid >> 6;
  if ((tid & 63) == 0) sred[wid] = mx;
  __syncthreads();
  mx = fmaxf(fmaxf(sred[0], sred[1]), fmaxf(sred[2], sred[3]));
  v0.x = __expf(v0.x - mx); v0.y = __expf(v0.y - mx);
  v0.z = __expf(v0.z - mx); v0.w = __expf(v0.w - mx);
  v1.x = __expf(v1.x - mx); v1.y = __expf(v1.y - mx);
  v1.z = __expf(v1.z - mx); v1.w = __expf(v1.w - mx);
  float s = v0.x + v0.y + v0.z + v0.w + v1.x + v1.y + v1.z + v1.w;
#pragma unroll
  for (int off = 32; off > 0; off >>= 1)
    s += __shfl_xor(s, off, 64);
  if ((tid & 63) == 0) sred[4 + wid] = s;
  __syncthreads();
  s = sred[4] + sred[5] + sred[6] + sred[7];
  const float inv = 1.0f / s;
  ushort4 o0, o1;
  o0.x = f2bf(v0.x * inv); o0.y = f2bf(v0.y * inv);
  o0.z = f2bf(v0.z * inv); o0.w = f2bf(v0.w * inv);
  o1.x = f2bf(v1.x * inv); o1.y = f2bf(v1.y * inv);
  o1.z = f2bf(v1.z * inv); o1.w = f2bf(v1.w * inv);
  *(ushort4*)(wout + tid * 8)     = o0;
  *(ushort4*)(wout + tid * 8 + 4) = o1;
}

// ===========================================================================
// Shared staging helpers. LDS k-chunk swizzle (T2): LDS[row][c] holds global
// chunk c ^ ((row>>1)&3) (16B chunks, involution), applied on the pre-swizzled
// *global source* address (LDS dest linear, m104). Read side uses
// ksw = (q ^ ((l16>>1)&3))*8 which exactly inverts it.
// ===========================================================================
__device__ __forceinline__ void stage256(
    const unsigned short* __restrict__ P, int ld, int r0, int kk,
    unsigned short* lds, int tid)
{
  const int ke = (((tid & 3) ^ ((tid >> 3) & 3)) << 3);
  const int row = r0 + (tid >> 2);
  g2l16(P + (size_t)row * ld + kk + ke, lds + tid * 8);
  g2l16(P + (size_t)(row + 128) * ld + kk + ke, lds + 4096 + tid * 8);
}
__device__ __forceinline__ void stage128(
    const unsigned short* __restrict__ P, int ld, int r0, int kk,
    unsigned short* lds, int tid)
{
  const int ke = (((tid & 3) ^ ((tid >> 3) & 3)) << 3);
  const int row = r0 + (tid >> 2);
  g2l16(P + (size_t)row * ld + kk + ke, lds + tid * 8);
}

// ===========================================================================
// 256x256 / BK=64 / 8-wave / 4-phase bf16 GEMM (T1+T2+T3+T4+T5). Proven R1.
// ===========================================================================
template<int CONVA>
__device__ __forceinline__ void stage_half(
    const unsigned short* __restrict__ P, int ld, int r0, int t, int ks,
    unsigned short* lds, int tid)
{
  const int bk = t * 64 + ks * 32;
  const int ke = (((tid & 3) ^ ((tid >> 3) & 3)) << 3);
  int rowbase, kcol;
  if constexpr (CONVA) {
    const int seg = bk >> 10;                 // block-uniform (8|ke, 32|bk)
    kcol = (bk & 1023) + ke;
    rowbase = r0 + (tid >> 2) + seg - 1;      // guard rows absorb -1/+2
  } else {
    kcol = bk + ke;
    rowbase = r0 + (tid >> 2);
  }
#pragma unroll
  for (int c = 0; c < 2; ++c)
    g2l16(P + (ptrdiff_t)(rowbase + c * 128) * ld + kcol,
          lds + c * 4096 + tid * 8);
}

template<int OUTBF, int EPI, int CONVA>
__global__ __launch_bounds__(512, 2) void gemm256_k(
    const unsigned short* __restrict__ A, long long sA, int lda,
    const unsigned short* __restrict__ B, long long sB, int ldb,
    void* __restrict__ Cv, long long sC, int ldc,
    int K, const float* __restrict__ bias)
{
  __shared__ __align__(16) unsigned short As[2][2][256 * 32];
  __shared__ __align__(16) unsigned short Bs[2][2][256 * 32];
  const int tid = threadIdx.x;
  int bxi = blockIdx.x, byi = blockIdx.y, bzi = blockIdx.z;
  xcd_swz(bxi, byi, bzi);
  A += (size_t)bzi * sA;
  B += (size_t)bzi * sB;
  const int bm = byi * 256;
  const int bn = bxi * 256;
  const int wave = tid >> 6, lane = tid & 63;
  const int wr = wave >> 2, wcn = wave & 3;   // 2x4 wave grid, 128x64 C/wave
  const int q = lane >> 4, l16 = lane & 15;
  const int ksw = ((q ^ ((l16 >> 1) & 3)) << 3);       // swizzled k-read off
  const int abase = (wr * 128 + l16) * 32 + ksw;
  const int bbase = (wcn * 64 + l16) * 32 + ksw;

  f32x4 acc[8][4];
#pragma unroll
  for (int i = 0; i < 8; ++i)
#pragma unroll
    for (int j = 0; j < 4; ++j)
      acc[i][j] = (f32x4){0.f, 0.f, 0.f, 0.f};

  const int T = K >> 6;

  stage_half<CONVA>(A, lda, bm, 0, 0, &As[0][0][0], tid);
  stage_half<0>   (B, ldb, bn, 0, 0, &Bs[0][0][0], tid);
  stage_half<CONVA>(A, lda, bm, 0, 1, &As[0][1][0], tid);
  stage_half<0>   (B, ldb, bn, 0, 1, &Bs[0][1][0], tid);
  VMCNT(4);
  BARX();

  bf8 af[4], bfr[4];
  for (int t = 0; t < T; ++t) {
    const int buf = t & 1;
    unsigned short* An0 = &As[buf ^ 1][0][0];
    unsigned short* An1 = &As[buf ^ 1][1][0];
    unsigned short* Bn0 = &Bs[buf ^ 1][0][0];
    unsigned short* Bn1 = &Bs[buf ^ 1][1][0];
    const bool next = (t + 1 < T);

    // ---- phase 0: ks0, i 0..3 ----
#pragma unroll
    for (int j = 0; j < 4; ++j) bfr[j] = *(const bf8*)&Bs[buf][0][bbase + j * 512];
#pragma unroll
    for (int m = 0; m < 4; ++m) af[m] = *(const bf8*)&As[buf][0][abase + m * 512];
    if (next) stage_half<CONVA>(A, lda, bm, t + 1, 0, An0, tid);
    BARX();
    __builtin_amdgcn_s_setprio(1);
#pragma unroll
    for (int m = 0; m < 4; ++m)
#pragma unroll
      for (int j = 0; j < 4; ++j)
        acc[m][j] = __builtin_amdgcn_mfma_f32_16x16x32_bf16(af[m], bfr[j], acc[m][j], 0, 0, 0);
    __builtin_amdgcn_s_setprio(0);
    BARX();

    // ---- phase 1: ks0, i 4..7 ----
#pragma unroll
    for (int m = 0; m < 4; ++m) af[m] = *(const bf8*)&As[buf][0][abase + (4 + m) * 512];
    if (next) { stage_half<0>(B, ldb, bn, t + 1, 0, Bn0, tid); VMCNT(4); }
    else      { VMCNT(0); }
    BARX();
    __builtin_amdgcn_s_setprio(1);
#pragma unroll
    for (int m = 0; m < 4; ++m)
#pragma unroll
      for (int j = 0; j < 4; ++j)
        acc[4 + m][j] = __builtin_amdgcn_mfma_f32_16x16x32_bf16(af[m], bfr[j], acc[4 + m][j], 0, 0, 0);
    __builtin_amdgcn_s_setprio(0);
    BARX();

    // ---- phase 2: ks1, i 0..3 ----
#pragma unroll
    for (int j = 0; j < 4; ++j) bfr[j] = *(const bf8*)&Bs[buf][1][bbase + j * 512];
#pragma unroll
    for (int m = 0; m < 4; ++m) af[m] = *(const bf8*)&As[buf][1][abase + m * 512];
    if (next) stage_half<CONVA>(A, lda, bm, t + 1, 1, An1, tid);
    BARX();
    __builtin_amdgcn_s_setprio(1);
#pragma unroll
    for (int m = 0; m < 4; ++m)
#pragma unroll
      for (int j = 0; j < 4; ++j)
        acc[m][j] = __builtin_amdgcn_mfma_f32_16x16x32_bf16(af[m], bfr[j], acc[m][j], 0, 0, 0);
    __builtin_amdgcn_s_setprio(0);
    BARX();

    // ---- phase 3: ks1, i 4..7 ----
#pragma unroll
    for (int m = 0; m < 4; ++m) af[m] = *(const bf8*)&As[buf][1][abase + (4 + m) * 512];
    if (next) { stage_half<0>(B, ldb, bn, t + 1, 1, Bn1, tid); VMCNT(4); }
    BARX();
    __builtin_amdgcn_s_setprio(1);
#pragma unroll
    for (int m = 0; m < 4; ++m)
#pragma unroll
      for (int j = 0; j < 4; ++j)
        acc[4 + m][j] = __builtin_amdgcn_mfma_f32_16x16x32_bf16(af[m], bfr[j], acc[4 + m][j], 0, 0, 0);
    __builtin_amdgcn_s_setprio(0);
    BARX();
  }

  float* Cf          = (float*)Cv          + (size_t)bzi * sC;
  unsigned short* Cb = (unsigned short*)Cv + (size_t)bzi * sC;
#pragma unroll
  for (int j = 0; j < 4; ++j) {
    const int col = bn + wcn * 64 + j * 16 + l16;
    float bv = 0.f;
    if constexpr (EPI >= 1) bv = bias[col];
#pragma unroll
    for (int i = 0; i < 8; ++i) {
      const int row0 = bm + wr * 128 + i * 16 + q * 4;
#pragma unroll
      for (int r = 0; r < 4; ++r) {
        float v = acc[i][j][r];
        if constexpr (EPI >= 1) v += bv;
        if constexpr (EPI == 2) v = fmaxf(v, 0.f);
        if constexpr (OUTBF) Cb[(size_t)(row0 + r) * ldc + col] = f2bf(v);
        else                 Cf[(size_t)(row0 + r) * ldc + col] = v;
      }
    }
  }
}

// ===========================================================================
// 128x256 / BK=64 / 8-wave / 2-phase bf16 GEMM. 96 KiB LDS, grid 2x denser
// than gemm256 — for the M*N-small GEMMs (attn, dense) that only fill half
// the machine at 256x256. Per phase: 3 staging loads (A-half 1, B-half 2);
// VMCNT(3) at each phase end leaves exactly next ks-half (3 loads) in flight.
// ===========================================================================
template<int OUTBF, int EPI>
__global__ __launch_bounds__(512, 2) void gemm128_k(
    const unsigned short* __restrict__ A, long long sA, int lda,
    const unsigned short* __restrict__ B, long long sB, int ldb,
    void* __restrict__ Cv, long long sC, int ldc,
    int K, const float* __restrict__ bias)
{
  __shared__ __align__(16) unsigned short As[2][2][128 * 32];  // 32 KiB
  __shared__ __align__(16) unsigned short Bs[2][2][256 * 32];  // 64 KiB
  const int tid = threadIdx.x;
  int bxi = blockIdx.x, byi = blockIdx.y, bzi = blockIdx.z;
  xcd_swz(bxi, byi, bzi);
  A += (size_t)bzi * sA;
  B += (size_t)bzi * sB;
  const int bm = byi * 128;
  const int bn = bxi * 256;
  const int wave = tid >> 6, lane = tid & 63;
  const int wr = wave >> 2, wcn = wave & 3;   // 2x4 wave grid, 64x64 C/wave
  const int q = lane >> 4, l16 = lane & 15;
  const int ksw = ((q ^ ((l16 >> 1) & 3)) << 3);
  const int abase = (wr * 64 + l16) * 32 + ksw;
  const int bbase = (wcn * 64 + l16) * 32 + ksw;

  f32x4 acc[4][4];
#pragma unroll
  for (int i = 0; i < 4; ++i)
#pragma unroll
    for (int j = 0; j < 4; ++j)
      acc[i][j] = (f32x4){0.f, 0.f, 0.f, 0.f};

  const int T = K >> 6;

  stage128(A, lda, bm, 0,  &As[0][0][0], tid);
  stage256(B, ldb, bn, 0,  &Bs[0][0][0], tid);
  stage128(A, lda, bm, 32, &As[0][1][0], tid);
  stage256(B, ldb, bn, 32, &Bs[0][1][0], tid);
  VMCNT(3);
  BARX();

  bf8 af[4], bfr[4];
  for (int t = 0; t < T; ++t) {
    const int buf = t & 1;
    const bool next = (t + 1 < T);
    const int kk = (t + 1) * 64;

    // ---- phase 0: ks0 ----
#pragma unroll
    for (int j = 0; j < 4; ++j) bfr[j] = *(const bf8*)&Bs[buf][0][bbase + j * 512];
#pragma unroll
    for (int m = 0; m < 4; ++m) af[m] = *(const bf8*)&As[buf][0][abase + m * 512];
    if (next) {
      stage128(A, lda, bm, kk,      &As[buf ^ 1][0][0], tid);
      stage256(B, ldb, bn, kk,      &Bs[buf ^ 1][0][0], tid);
      VMCNT(3);
    } else { VMCNT(0); }
    BARX();
    __builtin_amdgcn_s_setprio(1);
#pragma unroll
    for (int m = 0; m < 4; ++m)
#pragma unroll
      for (int j = 0; j < 4; ++j)
        acc[m][j] = __builtin_amdgcn_mfma_f32_16x16x32_bf16(af[m], bfr[j], acc[m][j], 0, 0, 0);
    __builtin_amdgcn_s_setprio(0);
    BARX();

    // ---- phase 1: ks1 ----
#pragma unroll
    for (int j = 0; j < 4; ++j) bfr[j] = *(const bf8*)&Bs[buf][1][bbase + j * 512];
#pragma unroll
    for (int m = 0; m < 4; ++m) af[m] = *(const bf8*)&As[buf][1][abase + m * 512];
    if (next) {
      stage128(A, lda, bm, kk + 32, &As[buf ^ 1][1][0], tid);
      stage256(B, ldb, bn, kk + 32, &Bs[buf ^ 1][1][0], tid);
      VMCNT(3);
    }
    BARX();
    __builtin_amdgcn_s_setprio(1);
#pragma unroll
    for (int m = 0; m < 4; ++m)
#pragma unroll
      for (int j = 0; j < 4; ++j)
        acc[m][j] = __builtin_amdgcn_mfma_f32_16x16x32_bf16(af[m], bfr[j], acc[m][j], 0, 0, 0);
    __builtin_amdgcn_s_setprio(0);
    BARX();
  }

  float* Cf          = (float*)Cv          + (size_t)bzi * sC;
  unsigned short* Cb = (unsigned short*)Cv + (size_t)bzi * sC;
#pragma unroll
  for (int j = 0; j < 4; ++j) {
    const int col = bn + wcn * 64 + j * 16 + l16;
    float bv = 0.f;
    if constexpr (EPI >= 1) bv = bias[col];
#pragma unroll
    for (int i = 0; i < 4; ++i) {
      const int row0 = bm + wr * 64 + i * 16 + q * 4;
#pragma unroll
      for (int r = 0; r < 4; ++r) {
        float v = acc[i][j][r];
        if constexpr (EPI >= 1) v += bv;
        if constexpr (EPI == 2) v = fmaxf(v, 0.f);
        if constexpr (OUTBF) Cb[(size_t)(row0 + r) * ldc + col] = f2bf(v);
        else                 Cf[(size_t)(row0 + r) * ldc + col] = v;
      }
    }
  }
}

// ===========================================================================
// Fused hi/lo logits GEMM, 256x256 / BK=32 / 8-wave / 4-phase.
// C = Ah.Bh^T + Ah.Bl^T + Al.Bh^T (fp32). LDS: 4 mats x 2 bufs x 16KiB =
// 128 KiB. Role map onto the proven gemm256 schedule: {Ah,Bh} = "ks0 half"
// (read p0/p1), {Al,Bl} = "ks1 half" (read p2/p3). Staging order per tile:
// p0 Ah(t+1), p1 Bh(t+1) + VMCNT(4) [guards Al,Bl(t)], p2 Al(t+1),
// p3 Bl(t+1) + VMCNT(4) [guards Ah,Bh(t+1)]. 96 MFMA/tile/wave.
// ===========================================================================
__global__ __launch_bounds__(512, 2) void gemm_logits256_k(
    const unsigned short* __restrict__ Ah, const unsigned short* __restrict__ Al,
    const unsigned short* __restrict__ Bh, const unsigned short* __restrict__ Bl,
    float* __restrict__ C)
{
  __shared__ __align__(16) unsigned short AsH[2][256 * 32];
  __shared__ __align__(16) unsigned short AsL[2][256 * 32];
  __shared__ __align__(16) unsigned short BsH[2][256 * 32];
  __shared__ __align__(16) unsigned short BsL[2][256 * 32];
  const int tid = threadIdx.x;
  int bxi = blockIdx.x, byi = blockIdx.y, bzi = blockIdx.z;
  xcd_swz(bxi, byi, bzi);
  const long long SE = (long long)TT * HID;
  Ah += (size_t)bzi * SE; Al += (size_t)bzi * SE;
  Bh += (size_t)bzi * SE; Bl += (size_t)bzi * SE;
  C  += (size_t)bzi * TT * TT;
  const int bm = byi * 256;
  const int bn = bxi * 256;
  const int wave = tid >> 6, lane = tid & 63;
  const int wr = wave >> 2, wcn = wave & 3;   // 2x4 wave grid, 128x64 C/wave
  const int q = lane >> 4, l16 = lane & 15;
  const int ksw = ((q ^ ((l16 >> 1) & 3)) << 3);
  const int abase = (wr * 128 + l16) * 32 + ksw;
  const int bbase = (wcn * 64 + l16) * 32 + ksw;

  f32x4 acc[8][4];
#pragma unroll
  for (int i = 0; i < 8; ++i)
#pragma unroll
    for (int j = 0; j < 4; ++j)
      acc[i][j] = (f32x4){0.f, 0.f, 0.f, 0.f};

  const int T = HID / 32;   // 32 K-tiles of BK=32

  stage256(Ah, HID, bm, 0, &AsH[0][0], tid);
  stage256(Bh, HID, bn, 0, &BsH[0][0], tid);
  stage256(Al, HID, bm, 0, &AsL[0][0], tid);
  stage256(Bl, HID, bn, 0, &BsL[0][0], tid);
  VMCNT(4);
  BARX();

  bf8 bh[4], bl[4], a0[4], a1[4], a2[4], a3[4];
  for (int t = 0; t < T; ++t) {
    const int buf = t & 1;
    const bool next = (t + 1 < T);
    const int kk = (t + 1) * 32;

    // ---- phase 0: Ah(lo-rows) x Bh ----
#pragma unroll
    for (int j = 0; j < 4; ++j) bh[j] = *(const bf8*)&BsH[buf][bbase + j * 512];
#pragma unroll
    for (int m = 0; m < 4; ++m) a0[m] = *(const bf8*)&AsH[buf][abase + m * 512];
    if (next) stage256(Ah, HID, bm, kk, &AsH[buf ^ 1][0], tid);
    BARX();
    __builtin_amdgcn_s_setprio(1);
#pragma unroll
    for (int m = 0; m < 4; ++m)
#pragma unroll
      for (int j = 0; j < 4; ++j)
        acc[m][j] = __builtin_amdgcn_mfma_f32_16x16x32_bf16(a0[m], bh[j], acc[m][j], 0, 0, 0);
    __builtin_amdgcn_s_setprio(0);
    BARX();

    // ---- phase 1: Ah(hi-rows) x Bh ----
#pragma unroll
    for (int m = 0; m < 4; ++m) a1[m] = *(const bf8*)&AsH[buf][abase + (4 + m) * 512];
    if (next) { stage256(Bh, HID, bn, kk, &BsH[buf ^ 1][0], tid); VMCNT(4); }
    else      { VMCNT(0); }
    BARX();
    __builtin_amdgcn_s_setprio(1);
#pragma unroll
    for (int m = 0; m < 4; ++m)
#pragma unroll
      for (int j = 0; j < 4; ++j)
        acc[4 + m][j] = __builtin_amdgcn_mfma_f32_16x16x32_bf16(a1[m], bh[j], acc[4 + m][j], 0, 0, 0);
    __builtin_amdgcn_s_setprio(0);
    BARX();

    // ---- phase 2: Ah(lo) x Bl  +  Al(lo) x Bh ----
#pragma unroll
    for (int j = 0; j < 4; ++j) bl[j] = *(const bf8*)&BsL[buf][bbase + j * 512];
#pragma unroll
    for (int m = 0; m < 4; ++m) a2[m] = *(const bf8*)&AsL[buf][abase + m * 512];
    if (next) stage256(Al, HID, bm, kk, &AsL[buf ^ 1][0], tid);
    BARX();
    __builtin_amdgcn_s_setprio(1);
#pragma unroll
    for (int m = 0; m < 4; ++m)
#pragma unroll
      for (int j = 0; j < 4; ++j) {
        acc[m][j] = __builtin_amdgcn_mfma_f32_16x16x32_bf16(a0[m], bl[j], acc[m][j], 0, 0, 0);
        acc[m][j] = __builtin_amdgcn_mfma_f32_16x16x32_bf16(a2[m], bh[j], acc[m][j], 0, 0, 0);
      }
    __builtin_amdgcn_s_setprio(0);
    BARX();

    // ---- phase 3: Ah(hi) x Bl  +  Al(hi) x Bh ----
#pragma unroll
    for (int m = 0; m < 4; ++m) a3[m] = *(const bf8*)&AsL[buf][abase + (4 + m) * 512];
    if (next) { stage256(Bl, HID, bn, kk, &BsL[buf ^ 1][0], tid); VMCNT(4); }
    BARX();
    __builtin_amdgcn_s_setprio(1);
#pragma unroll
    for (int m = 0; m < 4; ++m)
#pragma unroll
      for (int j = 0; j < 4; ++j) {
        acc[4 + m][j] = __builtin_amdgcn_mfma_f32_16x16x32_bf16(a1[m], bl[j], acc[4 + m][j], 0, 0, 0);
        acc[4 + m][j] = __builtin_amdgcn_mfma_f32_16x16x32_bf16(a3[m], bh[j], acc[4 + m][j], 0, 0, 0);
      }
    __builtin_amdgcn_s_setprio(0);
    BARX();
  }

#pragma unroll
  for (int j = 0; j < 4; ++j) {
    const int col = bn + wcn * 64 + j * 16 + l16;
#pragma unroll
    for (int i = 0; i < 8; ++i) {
      const int row0 = bm + wr * 128 + i * 16 + q * 4;
#pragma unroll
      for (int r = 0; r < 4; ++r)
        C[(size_t)(row0 + r) * TT + col] = acc[i][j][r];
    }
  }
}

extern "C" void kernel_launch(void* const* d_in, const int* in_sizes, int n_in,
                              void* d_out, int out_size, void* d_ws, size_t ws_size,
                              hipStream_t stream)
{
  const int*   inputs     = (const int*)d_in[0];
  const int*   targets    = (const int*)d_in[1];
  const float* input_emb  = (const float*)d_in[2];
  const float* target_emb = (const float*)d_in[3];
  const float* conv_w     = (const float*)d_in[4];
  const float* conv_b     = (const float*)d_in[5];
  const float* dense_w    = (const float*)d_in[6];
  const float* dense_b    = (const float*)d_in[7];
  float* out = (float*)d_out;

  const long long SE = (long long)TT * HID;     // elems per batch (te/ie)
  const size_t SZ = (size_t)NB * SE * 2;        // 16,777,216 B bf16 region

  // workspace map (167,772,160 B total, proven capacity):
  // [0,SZ)        te_hi          -> ieT after logits
  // [SZ,..)       te_lo          -> attn padded (NB*PR+1 rows = 16,787,456 B)
  // [2SZ,3SZ)     ie_hi          -> convwb @ 2SZ+16K (25.2 MB, spans ie_lo)
  // [3SZ,4SZ)     ie_lo
  // [4SZ,4SZ+67M) logit fp32     -> hb bf16 after softmax
  // [4SZ+67M,end) Wbf bf16       -> densewb after attn GEMM
  char* base = (char*)d_ws;
  unsigned short* te_hi = (unsigned short*)(base);
  unsigned short* te_lo = (unsigned short*)(base + SZ);
  unsigned short* ie_hi = (unsigned short*)(base + 2 * SZ);
  unsigned short* ie_lo = (unsigned short*)(base + 3 * SZ);
  float*          logit = (float*)         (base + 4 * SZ);
  unsigned short* Wbf   = (unsigned short*)(base + 4 * SZ + (size_t)NB * TT * TT * 4);
  unsigned short* ieT     = (unsigned short*)(base);
  unsigned short* attnP   = (unsigned short*)(base + SZ);              // padded buffer base
  unsigned short* attnD   = attnP + (size_t)HID;                       // first data row
  unsigned short* convwb  = (unsigned short*)(base + 2 * SZ + 16384);
  unsigned short* hb      = (unsigned short*)(base + 4 * SZ);
  unsigned short* densewb = (unsigned short*)Wbf;

  // 1) gathers: te raw, ie scaled by sqrt(H)=32  (logits = te_raw . ie_scaled)
  gather_split_k<<<NB * TT, 256, 0, stream>>>(targets, target_emb, te_hi, te_lo, 1.0f);
  gather_split_k<<<NB * TT, 256, 0, stream>>>(inputs,  input_emb,  ie_hi, ie_lo, 32.0f);

  // 2) fused hi/lo logits (256² 4-phase)
  gemm_logits256_k<<<dim3(TT / 256, TT / 256, NB), 512, 0, stream>>>(
      te_hi, te_lo, ie_hi, ie_lo, logit);

  // 3) ieT[h][s] = ie_hi[s][h]  (overwrites te_hi, dead)
  transpose_bf_k<unsigned short><<<dim3(HID / 32, TT / 32, NB), 256, 0, stream>>>(
      ie_hi, ieT, TT, HID, SE, SE);

  // 4) softmax -> bf16 W
  softmax_bf_k<<<NB * TT, 256, 0, stream>>>(logit, Wbf);

  // 5) guard rows + attn[t][h] = W[t][s] . ieT[h][s] -> padded bf16 buffer
  zero_guard_k<<<NB + 1, 256, 0, stream>>>(attnP);
  gemm128_k<1, 0><<<dim3(HID / 256, TT / 128, NB), 512, 0, stream>>>(
      Wbf, (long long)TT * TT, TT, ieT, SE, TT,
      attnD, (long long)PR * HID, HID, TT, nullptr);

  // 6) weight transposes (convwb over dead ie region; densewb over dead Wbf)
  transpose_bf_k<float><<<dim3(UD / 32, (3 * HID) / 32, 1), 256, 0, stream>>>(
      conv_w, convwb, 3 * HID, UD, 0, 0);
  transpose_bf_k<float><<<dim3(HID / 32, UD / 32, 1), 256, 0, stream>>>(
      dense_w, densewb, UD, HID, 0, 0);

  // 7) conv: h = relu(b + im2col(attn).convwb^T) -> bf16 (over dead logit)
  gemm256_k<1, 2, 1><<<dim3(UD / 256, TT / 256, NB), 512, 0, stream>>>(
      attnD, (long long)PR * HID, HID, convwb, 0, 3 * HID,
      hb, (long long)TT * UD, UD, 3 * HID, conv_b);

  // 8) dense: out = b + h.densewb^T  (fp32 out)
  gemm128_k<0, 1><<<dim3(HID / 256, TT / 128, NB), 512, 0, stream>>>(
      hb, (long long)TT * UD, UD, densewb, 0, UD,
      out, SE, HID, UD, dense_b);
}

// Round 3
// 724.509 us; speedup vs baseline: 1.5604x; 1.0000x over previous
//
#include <hip/hip_runtime.h>
#include <cstddef>

static constexpr int HID = 1024;   // hidden
static constexpr int NB  = 4;      // batch
static constexpr int TT  = 2048;   // sequence (Ti == Tt)
static constexpr int UD  = 4096;   // conv units
static constexpr int PR  = TT + 1; // padded row stride (guard row per batch)

typedef short bf8    __attribute__((ext_vector_type(8)));  // 8 bf16 (4 VGPRs)
typedef float f32x4  __attribute__((ext_vector_type(4)));  // MFMA C/D frag

__device__ __forceinline__ unsigned short f2bf(float x) {
  unsigned int u = __float_as_uint(x);
  u += 0x7fffu + ((u >> 16) & 1u);          // round-to-nearest-even
  return (unsigned short)(u >> 16);
}
__device__ __forceinline__ float bf2f(unsigned short h) {
  return __uint_as_float(((unsigned int)h) << 16);
}
__device__ __forceinline__ unsigned short cvt_bf(float x) { return f2bf(x); }
__device__ __forceinline__ unsigned short cvt_bf(unsigned short x) { return x; }

// async global->LDS, 16B per lane. LDS dest must be wave-uniform base + lane*16
// (m104/m108) — all staging below satisfies this by construction.
__device__ __forceinline__ void g2l16(const unsigned short* g, unsigned short* l) {
  __builtin_amdgcn_global_load_lds(
      (const __attribute__((address_space(1))) unsigned int*)g,
      (__attribute__((address_space(3))) unsigned int*)l, 16, 0, 0);
}

#define BARX() __builtin_amdgcn_s_barrier()
#define VMCNT(n) asm volatile("s_waitcnt vmcnt(" #n ")" ::: "memory")

// T1: bijective XCD-chunked block swizzle (requires nwg % 8 == 0 — all our
// MFMA grids are multiples of 8).
__device__ __forceinline__ void xcd_swz(int& bx, int& by, int& bz) {
  const int gx = gridDim.x, gy = gridDim.y;
  const int nwg = gx * gy * (int)gridDim.z;
  int flat = bx + gx * (by + gy * bz);
  const int cpx = nwg >> 3;
  flat = (flat & 7) * cpx + (flat >> 3);
  bx = flat % gx; flat /= gx;
  by = flat % gy; bz = flat / gy;
}

// ---- gather row + scale, split into bf16 hi/lo:  hi+lo ~= scale*emb[idx] ----
__global__ __launch_bounds__(256) void gather_split_k(
    const int* __restrict__ idx, const float* __restrict__ emb,
    unsigned short* __restrict__ hi, unsigned short* __restrict__ lo, float scale)
{
  const int row = blockIdx.x;
  const int r = idx[row];
  const int c = threadIdx.x * 4;
  float4 v = *(const float4*)(emb + (size_t)r * HID + c);
  v.x *= scale; v.y *= scale; v.z *= scale; v.w *= scale;
  ushort4 h, l;
  h.x = f2bf(v.x); h.y = f2bf(v.y); h.z = f2bf(v.z); h.w = f2bf(v.w);
  l.x = f2bf(v.x - bf2f(h.x)); l.y = f2bf(v.y - bf2f(h.y));
  l.z = f2bf(v.z - bf2f(h.z)); l.w = f2bf(v.w - bf2f(h.w));
  *(ushort4*)(hi + (size_t)row * HID + c) = h;
  *(ushort4*)(lo + (size_t)row * HID + c) = l;
}

// ---- zero the 5 guard rows of the padded attn buffer ----------------------
__global__ __launch_bounds__(256) void zero_guard_k(unsigned short* __restrict__ p)
{
  unsigned short* row = p + (size_t)blockIdx.x * PR * HID;
  *(ushort4*)(row + threadIdx.x * 4) = (ushort4){0, 0, 0, 0};
}

// ---- generic transpose to bf16: out[c][r] = bf16(in[r][c]) ----------------
template<typename TIN>
__global__ __launch_bounds__(256) void transpose_bf_k(
    const TIN* __restrict__ in, unsigned short* __restrict__ out,
    int R, int C, long long sIn, long long sOut)
{
  __shared__ unsigned short tile[32][33];
  in  += (size_t)blockIdx.z * sIn;
  out += (size_t)blockIdx.z * sOut;
  const int r0 = blockIdx.y * 32, c0 = blockIdx.x * 32;
  const int tc = threadIdx.x & 31, tr8 = threadIdx.x >> 5;
#pragma unroll
  for (int p = 0; p < 4; ++p) {
    const int r = tr8 + p * 8;
    tile[r][tc] = cvt_bf(in[(size_t)(r0 + r) * C + c0 + tc]);
  }
  __syncthreads();
#pragma unroll
  for (int p = 0; p < 4; ++p) {
    const int c = tr8 + p * 8;
    out[(size_t)(c0 + c) * R + r0 + tc] = tile[tc][c];
  }
}

// ---- row softmax over TT cols: fp32 in -> bf16 out ------------------------
__global__ __launch_bounds__(256) void softmax_bf_k(
    const float* __restrict__ L, unsigned short* __restrict__ W)
{
  const float* row = L + (size_t)blockIdx.x * TT;
  unsigned short* wout = W + (size_t)blockIdx.x * TT;
  const int tid = threadIdx.x;
  float4 v0 = ((const float4*)row)[tid * 2];
  float4 v1 = ((const float4*)row)[tid * 2 + 1];
  float mx = fmaxf(fmaxf(fmaxf(v0.x, v0.y), fmaxf(v0.z, v0.w)),
                   fmaxf(fmaxf(v1.x, v1.y), fmaxf(v1.z, v1.w)));
#pragma unroll
  for (int off = 32; off > 0; off >>= 1)
    mx = fmaxf(mx, __shfl_xor(mx, off, 64));
  __shared__ float sred[8];
  const int wid = tid >> 6;
  if ((tid & 63) == 0) sred[wid] = mx;
  __syncthreads();
  mx = fmaxf(fmaxf(sred[0], sred[1]), fmaxf(sred[2], sred[3]));
  v0.x = __expf(v0.x - mx); v0.y = __expf(v0.y - mx);
  v0.z = __expf(v0.z - mx); v0.w = __expf(v0.w - mx);
  v1.x = __expf(v1.x - mx); v1.y = __expf(v1.y - mx);
  v1.z = __expf(v1.z - mx); v1.w = __expf(v1.w - mx);
  float s = v0.x + v0.y + v0.z + v0.w + v1.x + v1.y + v1.z + v1.w;
#pragma unroll
  for (int off = 32; off > 0; off >>= 1)
    s += __shfl_xor(s, off, 64);
  if ((tid & 63) == 0) sred[4 + wid] = s;
  __syncthreads();
  s = sred[4] + sred[5] + sred[6] + sred[7];
  const float inv = 1.0f / s;
  ushort4 o0, o1;
  o0.x = f2bf(v0.x * inv); o0.y = f2bf(v0.y * inv);
  o0.z = f2bf(v0.z * inv); o0.w = f2bf(v0.w * inv);
  o1.x = f2bf(v1.x * inv); o1.y = f2bf(v1.y * inv);
  o1.z = f2bf(v1.z * inv); o1.w = f2bf(v1.w * inv);
  *(ushort4*)(wout + tid * 8)     = o0;
  *(ushort4*)(wout + tid * 8 + 4) = o1;
}

// ===========================================================================
// Staging helpers. LDS k-chunk swizzle (T2): LDS[row][c] holds global chunk
// c ^ ((row>>1)&3) (16B chunks, involution), applied on the pre-swizzled
// *global source* address (LDS dest linear, m104). Read side uses
// ksw = (q ^ ((l16>>1)&3))*8 which exactly inverts it.
// ===========================================================================
__device__ __forceinline__ void stage256(
    const unsigned short* __restrict__ P, int ld, int r0, int kk,
    unsigned short* lds, int tid)
{
  const int ke = (((tid & 3) ^ ((tid >> 3) & 3)) << 3);
  const int row = r0 + (tid >> 2);
  g2l16(P + (size_t)row * ld + kk + ke, lds + tid * 8);
  g2l16(P + (size_t)(row + 128) * ld + kk + ke, lds + 4096 + tid * 8);
}
__device__ __forceinline__ void stage128(
    const unsigned short* __restrict__ P, int ld, int r0, int kk,
    unsigned short* lds, int tid)
{
  const int ke = (((tid & 3) ^ ((tid >> 3) & 3)) << 3);
  const int row = r0 + (tid >> 2);
  g2l16(P + (size_t)row * ld + kk + ke, lds + tid * 8);
}

template<int CONVA>
__device__ __forceinline__ void stage_half(
    const unsigned short* __restrict__ P, int ld, int r0, int t, int ks,
    unsigned short* lds, int tid)
{
  const int bk = t * 64 + ks * 32;
  const int ke = (((tid & 3) ^ ((tid >> 3) & 3)) << 3);
  int rowbase, kcol;
  if constexpr (CONVA) {
    const int seg = bk >> 10;                 // block-uniform (8|ke, 32|bk)
    kcol = (bk & 1023) + ke;
    rowbase = r0 + (tid >> 2) + seg - 1;      // guard rows absorb -1/+2
  } else {
    kcol = bk + ke;
    rowbase = r0 + (tid >> 2);
  }
#pragma unroll
  for (int c = 0; c < 2; ++c)
    g2l16(P + (ptrdiff_t)(rowbase + c * 128) * ld + kcol,
          lds + c * 4096 + tid * 8);
}

// ===========================================================================
// 256x256 / BK=64 / 8-wave / 4-phase bf16 GEMM, DEEP pipeline (3 half-tiles
// in flight, m201-style). Half-tile H(t,ks) = A-half(2 loads) + B-half(2).
// Consumption: H(t,0) @ p0/p1(t), H(t,1) @ p2/p3(t).
// Staging: p0(t): A(t+1,ks1); p1(t): B(t+1,ks1) + VMCNT(8) [drains H(t,1),
// issued 4 phases earlier]; p2(t): A(t+2,ks0) -> As[buf][0] (just freed);
// p3(t): B(t+2,ks0) + VMCNT(8) [drains H(t+1,0)]. Steady outstanding = 12;
// oldest 4 are exactly the half needed next. Tails drain conservatively.
// WAR safety: every stage-issue is >= 2 barriers after the last read-issue
// of its target slot (same separation as the proven R1 structure).
// ===========================================================================
template<int OUTBF, int EPI, int CONVA>
__global__ __launch_bounds__(512, 2) void gemm256_k(
    const unsigned short* __restrict__ A, long long sA, int lda,
    const unsigned short* __restrict__ B, long long sB, int ldb,
    void* __restrict__ Cv, long long sC, int ldc,
    int K, const float* __restrict__ bias)
{
  __shared__ __align__(16) unsigned short As[2][2][256 * 32];
  __shared__ __align__(16) unsigned short Bs[2][2][256 * 32];
  const int tid = threadIdx.x;
  int bxi = blockIdx.x, byi = blockIdx.y, bzi = blockIdx.z;
  xcd_swz(bxi, byi, bzi);
  A += (size_t)bzi * sA;
  B += (size_t)bzi * sB;
  const int bm = byi * 256;
  const int bn = bxi * 256;
  const int wave = tid >> 6, lane = tid & 63;
  const int wr = wave >> 2, wcn = wave & 3;   // 2x4 wave grid, 128x64 C/wave
  const int q = lane >> 4, l16 = lane & 15;
  const int ksw = ((q ^ ((l16 >> 1) & 3)) << 3);       // swizzled k-read off
  const int abase = (wr * 128 + l16) * 32 + ksw;
  const int bbase = (wcn * 64 + l16) * 32 + ksw;

  f32x4 acc[8][4];
#pragma unroll
  for (int i = 0; i < 8; ++i)
#pragma unroll
    for (int j = 0; j < 4; ++j)
      acc[i][j] = (f32x4){0.f, 0.f, 0.f, 0.f};

  const int T = K >> 6;   // requires T >= 3 (all call sites: 32..64)

  // prologue: H(0,0), H(0,1), H(1,0)  (12 loads); drain H(0,0)
  stage_half<CONVA>(A, lda, bm, 0, 0, &As[0][0][0], tid);
  stage_half<0>   (B, ldb, bn, 0, 0, &Bs[0][0][0], tid);
  stage_half<CONVA>(A, lda, bm, 0, 1, &As[0][1][0], tid);
  stage_half<0>   (B, ldb, bn, 0, 1, &Bs[0][1][0], tid);
  stage_half<CONVA>(A, lda, bm, 1, 0, &As[1][0][0], tid);
  stage_half<0>   (B, ldb, bn, 1, 0, &Bs[1][0][0], tid);
  VMCNT(8);
  BARX();

  bf8 af[4], bfr[4];
  for (int t = 0; t < T; ++t) {
    const int buf = t & 1;

    // ---- phase 0: ks0, i 0..3 ; stage A(t+1, ks1) ----
#pragma unroll
    for (int j = 0; j < 4; ++j) bfr[j] = *(const bf8*)&Bs[buf][0][bbase + j * 512];
#pragma unroll
    for (int m = 0; m < 4; ++m) af[m] = *(const bf8*)&As[buf][0][abase + m * 512];
    if (t + 1 < T) stage_half<CONVA>(A, lda, bm, t + 1, 1, &As[buf ^ 1][1][0], tid);
    BARX();
    __builtin_amdgcn_s_setprio(1);
#pragma unroll
    for (int m = 0; m < 4; ++m)
#pragma unroll
      for (int j = 0; j < 4; ++j)
        acc[m][j] = __builtin_amdgcn_mfma_f32_16x16x32_bf16(af[m], bfr[j], acc[m][j], 0, 0, 0);
    __builtin_amdgcn_s_setprio(0);
    BARX();

    // ---- phase 1: ks0, i 4..7 ; stage B(t+1, ks1) ; drain H(t,1) ----
#pragma unroll
    for (int m = 0; m < 4; ++m) af[m] = *(const bf8*)&As[buf][0][abase + (4 + m) * 512];
    if (t + 1 < T) stage_half<0>(B, ldb, bn, t + 1, 1, &Bs[buf ^ 1][1][0], tid);
    if (t < T - 1) { VMCNT(8); } else { VMCNT(0); }
    BARX();
    __builtin_amdgcn_s_setprio(1);
#pragma unroll
    for (int m = 0; m < 4; ++m)
#pragma unroll
      for (int j = 0; j < 4; ++j)
        acc[4 + m][j] = __builtin_amdgcn_mfma_f32_16x16x32_bf16(af[m], bfr[j], acc[4 + m][j], 0, 0, 0);
    __builtin_amdgcn_s_setprio(0);
    BARX();

    // ---- phase 2: ks1, i 0..3 ; stage A(t+2, ks0) into freed slot ----
#pragma unroll
    for (int j = 0; j < 4; ++j) bfr[j] = *(const bf8*)&Bs[buf][1][bbase + j * 512];
#pragma unroll
    for (int m = 0; m < 4; ++m) af[m] = *(const bf8*)&As[buf][1][abase + m * 512];
    if (t + 2 < T) stage_half<CONVA>(A, lda, bm, t + 2, 0, &As[buf][0][0], tid);
    BARX();
    __builtin_amdgcn_s_setprio(1);
#pragma unroll
    for (int m = 0; m < 4; ++m)
#pragma unroll
      for (int j = 0; j < 4; ++j)
        acc[m][j] = __builtin_amdgcn_mfma_f32_16x16x32_bf16(af[m], bfr[j], acc[m][j], 0, 0, 0);
    __builtin_amdgcn_s_setprio(0);
    BARX();

    // ---- phase 3: ks1, i 4..7 ; stage B(t+2, ks0) ; drain H(t+1,0) ----
#pragma unroll
    for (int m = 0; m < 4; ++m) af[m] = *(const bf8*)&As[buf][1][abase + (4 + m) * 512];
    if (t + 2 < T) stage_half<0>(B, ldb, bn, t + 2, 0, &Bs[buf][0][0], tid);
    if (t < T - 2) { VMCNT(8); } else { VMCNT(0); }
    BARX();
    __builtin_amdgcn_s_setprio(1);
#pragma unroll
    for (int m = 0; m < 4; ++m)
#pragma unroll
      for (int j = 0; j < 4; ++j)
        acc[4 + m][j] = __builtin_amdgcn_mfma_f32_16x16x32_bf16(af[m], bfr[j], acc[4 + m][j], 0, 0, 0);
    __builtin_amdgcn_s_setprio(0);
    BARX();
  }

  float* Cf          = (float*)Cv          + (size_t)bzi * sC;
  unsigned short* Cb = (unsigned short*)Cv + (size_t)bzi * sC;
#pragma unroll
  for (int j = 0; j < 4; ++j) {
    const int col = bn + wcn * 64 + j * 16 + l16;
    float bv = 0.f;
    if constexpr (EPI >= 1) bv = bias[col];
#pragma unroll
    for (int i = 0; i < 8; ++i) {
      const int row0 = bm + wr * 128 + i * 16 + q * 4;
#pragma unroll
      for (int r = 0; r < 4; ++r) {
        float v = acc[i][j][r];
        if constexpr (EPI >= 1) v += bv;
        if constexpr (EPI == 2) v = fmaxf(v, 0.f);
        if constexpr (OUTBF) Cb[(size_t)(row0 + r) * ldc + col] = f2bf(v);
        else                 Cf[(size_t)(row0 + r) * ldc + col] = v;
      }
    }
  }
}

// ===========================================================================
// 128x256 / BK=64 / 8-wave / 2-phase bf16 GEMM, DEEP pipeline (3 half-tiles
// in flight). Half H(t,ks) = 3 loads (A 1, B 2). Consumption: H(t,0)@p0,
// H(t,1)@p1. Staging: p0(t): H(t+1,1) + VMCNT(6) [drains H(t,1)];
// p1(t): H(t+2,0) into freed slot + VMCNT(6) [drains H(t+1,0)].
// ===========================================================================
template<int OUTBF, int EPI>
__global__ __launch_bounds__(512, 2) void gemm128_k(
    const unsigned short* __restrict__ A, long long sA, int lda,
    const unsigned short* __restrict__ B, long long sB, int ldb,
    void* __restrict__ Cv, long long sC, int ldc,
    int K, const float* __restrict__ bias)
{
  __shared__ __align__(16) unsigned short As[2][2][128 * 32];  // 32 KiB
  __shared__ __align__(16) unsigned short Bs[2][2][256 * 32];  // 64 KiB
  const int tid = threadIdx.x;
  int bxi = blockIdx.x, byi = blockIdx.y, bzi = blockIdx.z;
  xcd_swz(bxi, byi, bzi);
  A += (size_t)bzi * sA;
  B += (size_t)bzi * sB;
  const int bm = byi * 128;
  const int bn = bxi * 256;
  const int wave = tid >> 6, lane = tid & 63;
  const int wr = wave >> 2, wcn = wave & 3;   // 2x4 wave grid, 64x64 C/wave
  const int q = lane >> 4, l16 = lane & 15;
  const int ksw = ((q ^ ((l16 >> 1) & 3)) << 3);
  const int abase = (wr * 64 + l16) * 32 + ksw;
  const int bbase = (wcn * 64 + l16) * 32 + ksw;

  f32x4 acc[4][4];
#pragma unroll
  for (int i = 0; i < 4; ++i)
#pragma unroll
    for (int j = 0; j < 4; ++j)
      acc[i][j] = (f32x4){0.f, 0.f, 0.f, 0.f};

  const int T = K >> 6;   // requires T >= 3 (call sites: 32, 64)

  // prologue: H(0,0), H(0,1), H(1,0); drain H(0,0)
  stage128(A, lda, bm, 0,  &As[0][0][0], tid);
  stage256(B, ldb, bn, 0,  &Bs[0][0][0], tid);
  stage128(A, lda, bm, 32, &As[0][1][0], tid);
  stage256(B, ldb, bn, 32, &Bs[0][1][0], tid);
  stage128(A, lda, bm, 64, &As[1][0][0], tid);
  stage256(B, ldb, bn, 64, &Bs[1][0][0], tid);
  VMCNT(6);
  BARX();

  bf8 af[4], bfr[4];
  for (int t = 0; t < T; ++t) {
    const int buf = t & 1;

    // ---- phase 0: ks0 ; stage H(t+1,1) ; drain H(t,1) ----
#pragma unroll
    for (int j = 0; j < 4; ++j) bfr[j] = *(const bf8*)&Bs[buf][0][bbase + j * 512];
#pragma unroll
    for (int m = 0; m < 4; ++m) af[m] = *(const bf8*)&As[buf][0][abase + m * 512];
    if (t + 1 < T) {
      const int kk = (t + 1) * 64 + 32;
      stage128(A, lda, bm, kk, &As[buf ^ 1][1][0], tid);
      stage256(B, ldb, bn, kk, &Bs[buf ^ 1][1][0], tid);
    }
    if (t < T - 1) { VMCNT(6); } else { VMCNT(0); }
    BARX();
    __builtin_amdgcn_s_setprio(1);
#pragma unroll
    for (int m = 0; m < 4; ++m)
#pragma unroll
      for (int j = 0; j < 4; ++j)
        acc[m][j] = __builtin_amdgcn_mfma_f32_16x16x32_bf16(af[m], bfr[j], acc[m][j], 0, 0, 0);
    __builtin_amdgcn_s_setprio(0);
    BARX();

    // ---- phase 1: ks1 ; stage H(t+2,0) into freed slot ; drain H(t+1,0) ----
#pragma unroll
    for (int j = 0; j < 4; ++j) bfr[j] = *(const bf8*)&Bs[buf][1][bbase + j * 512];
#pragma unroll
    for (int m = 0; m < 4; ++m) af[m] = *(const bf8*)&As[buf][1][abase + m * 512];
    if (t + 2 < T) {
      const int kk = (t + 2) * 64;
      stage128(A, lda, bm, kk, &As[buf][0][0], tid);
      stage256(B, ldb, bn, kk, &Bs[buf][0][0], tid);
    }
    if (t < T - 2) { VMCNT(6); } else { VMCNT(0); }
    BARX();
    __builtin_amdgcn_s_setprio(1);
#pragma unroll
    for (int m = 0; m < 4; ++m)
#pragma unroll
      for (int j = 0; j < 4; ++j)
        acc[m][j] = __builtin_amdgcn_mfma_f32_16x16x32_bf16(af[m], bfr[j], acc[m][j], 0, 0, 0);
    __builtin_amdgcn_s_setprio(0);
    BARX();
  }

  float* Cf          = (float*)Cv          + (size_t)bzi * sC;
  unsigned short* Cb = (unsigned short*)Cv + (size_t)bzi * sC;
#pragma unroll
  for (int j = 0; j < 4; ++j) {
    const int col = bn + wcn * 64 + j * 16 + l16;
    float bv = 0.f;
    if constexpr (EPI >= 1) bv = bias[col];
#pragma unroll
    for (int i = 0; i < 4; ++i) {
      const int row0 = bm + wr * 64 + i * 16 + q * 4;
#pragma unroll
      for (int r = 0; r < 4; ++r) {
        float v = acc[i][j][r];
        if constexpr (EPI >= 1) v += bv;
        if constexpr (EPI == 2) v = fmaxf(v, 0.f);
        if constexpr (OUTBF) Cb[(size_t)(row0 + r) * ldc + col] = f2bf(v);
        else                 Cf[(size_t)(row0 + r) * ldc + col] = v;
      }
    }
  }
}

// ===========================================================================
// Fused hi/lo logits GEMM, 256x256 / BK=32 / 8-wave / 4-phase, DEEP pipeline.
// Halves: Hh(t)={Ah,Bh} (read p0/p1), Hl(t)={Al,Bl} (read p2/p3); 2 loads per
// stage256 call, 4 per half. Staging: p0(t): Al(t+1); p1(t): Bl(t+1) +
// VMCNT(8) [drains Hl(t)]; p2(t): Ah(t+2) into freed AsH[buf]; p3(t):
// Bh(t+2) + VMCNT(8) [drains Hh(t+1)].
// ===========================================================================
__global__ __launch_bounds__(512, 2) void gemm_logits256_k(
    const unsigned short* __restrict__ Ah, const unsigned short* __restrict__ Al,
    const unsigned short* __restrict__ Bh, const unsigned short* __restrict__ Bl,
    float* __restrict__ C)
{
  __shared__ __align__(16) unsigned short AsH[2][256 * 32];
  __shared__ __align__(16) unsigned short AsL[2][256 * 32];
  __shared__ __align__(16) unsigned short BsH[2][256 * 32];
  __shared__ __align__(16) unsigned short BsL[2][256 * 32];
  const int tid = threadIdx.x;
  int bxi = blockIdx.x, byi = blockIdx.y, bzi = blockIdx.z;
  xcd_swz(bxi, byi, bzi);
  const long long SE = (long long)TT * HID;
  Ah += (size_t)bzi * SE; Al += (size_t)bzi * SE;
  Bh += (size_t)bzi * SE; Bl += (size_t)bzi * SE;
  C  += (size_t)bzi * TT * TT;
  const int bm = byi * 256;
  const int bn = bxi * 256;
  const int wave = tid >> 6, lane = tid & 63;
  const int wr = wave >> 2, wcn = wave & 3;   // 2x4 wave grid, 128x64 C/wave
  const int q = lane >> 4, l16 = lane & 15;
  const int ksw = ((q ^ ((l16 >> 1) & 3)) << 3);
  const int abase = (wr * 128 + l16) * 32 + ksw;
  const int bbase = (wcn * 64 + l16) * 32 + ksw;

  f32x4 acc[8][4];
#pragma unroll
  for (int i = 0; i < 8; ++i)
#pragma unroll
    for (int j = 0; j < 4; ++j)
      acc[i][j] = (f32x4){0.f, 0.f, 0.f, 0.f};

  const int T = HID / 32;   // 32 K-tiles of BK=32

  // prologue: Hh(0), Hl(0), Hh(1)  (12 loads); drain Hh(0)
  stage256(Ah, HID, bm, 0,  &AsH[0][0], tid);
  stage256(Bh, HID, bn, 0,  &BsH[0][0], tid);
  stage256(Al, HID, bm, 0,  &AsL[0][0], tid);
  stage256(Bl, HID, bn, 0,  &BsL[0][0], tid);
  stage256(Ah, HID, bm, 32, &AsH[1][0], tid);
  stage256(Bh, HID, bn, 32, &BsH[1][0], tid);
  VMCNT(8);
  BARX();

  bf8 bh[4], bl[4], a0[4], a1[4], a2[4], a3[4];
  for (int t = 0; t < T; ++t) {
    const int buf = t & 1;

    // ---- phase 0: Ah(lo-rows) x Bh ; stage Al(t+1) ----
#pragma unroll
    for (int j = 0; j < 4; ++j) bh[j] = *(const bf8*)&BsH[buf][bbase + j * 512];
#pragma unroll
    for (int m = 0; m < 4; ++m) a0[m] = *(const bf8*)&AsH[buf][abase + m * 512];
    if (t + 1 < T) stage256(Al, HID, bm, (t + 1) * 32, &AsL[buf ^ 1][0], tid);
    BARX();
    __builtin_amdgcn_s_setprio(1);
#pragma unroll
    for (int m = 0; m < 4; ++m)
#pragma unroll
      for (int j = 0; j < 4; ++j)
        acc[m][j] = __builtin_amdgcn_mfma_f32_16x16x32_bf16(a0[m], bh[j], acc[m][j], 0, 0, 0);
    __builtin_amdgcn_s_setprio(0);
    BARX();

    // ---- phase 1: Ah(hi-rows) x Bh ; stage Bl(t+1) ; drain Hl(t) ----
#pragma unroll
    for (int m = 0; m < 4; ++m) a1[m] = *(const bf8*)&AsH[buf][abase + (4 + m) * 512];
    if (t + 1 < T) stage256(Bl, HID, bn, (t + 1) * 32, &BsL[buf ^ 1][0], tid);
    if (t < T - 1) { VMCNT(8); } else { VMCNT(0); }
    BARX();
    __builtin_amdgcn_s_setprio(1);
#pragma unroll
    for (int m = 0; m < 4; ++m)
#pragma unroll
      for (int j = 0; j < 4; ++j)
        acc[4 + m][j] = __builtin_amdgcn_mfma_f32_16x16x32_bf16(a1[m], bh[j], acc[4 + m][j], 0, 0, 0);
    __builtin_amdgcn_s_setprio(0);
    BARX();

    // ---- phase 2: Ah(lo) x Bl  +  Al(lo) x Bh ; stage Ah(t+2) ----
#pragma unroll
    for (int j = 0; j < 4; ++j) bl[j] = *(const bf8*)&BsL[buf][bbase + j * 512];
#pragma unroll
    for (int m = 0; m < 4; ++m) a2[m] = *(const bf8*)&AsL[buf][abase + m * 512];
    if (t + 2 < T) stage256(Ah, HID, bm, (t + 2) * 32, &AsH[buf][0], tid);
    BARX();
    __builtin_amdgcn_s_setprio(1);
#pragma unroll
    for (int m = 0; m < 4; ++m)
#pragma unroll
      for (int j = 0; j < 4; ++j) {
        acc[m][j] = __builtin_amdgcn_mfma_f32_16x16x32_bf16(a0[m], bl[j], acc[m][j], 0, 0, 0);
        acc[m][j] = __builtin_amdgcn_mfma_f32_16x16x32_bf16(a2[m], bh[j], acc[m][j], 0, 0, 0);
      }
    __builtin_amdgcn_s_setprio(0);
    BARX();

    // ---- phase 3: Ah(hi) x Bl  +  Al(hi) x Bh ; stage Bh(t+2) ; drain Hh(t+1) ----
#pragma unroll
    for (int m = 0; m < 4; ++m) a3[m] = *(const bf8*)&AsL[buf][abase + (4 + m) * 512];
    if (t + 2 < T) stage256(Bh, HID, bn, (t + 2) * 32, &BsH[buf][0], tid);
    if (t < T - 2) { VMCNT(8); } else { VMCNT(0); }
    BARX();
    __builtin_amdgcn_s_setprio(1);
#pragma unroll
    for (int m = 0; m < 4; ++m)
#pragma unroll
      for (int j = 0; j < 4; ++j) {
        acc[4 + m][j] = __builtin_amdgcn_mfma_f32_16x16x32_bf16(a1[m], bl[j], acc[4 + m][j], 0, 0, 0);
        acc[4 + m][j] = __builtin_amdgcn_mfma_f32_16x16x32_bf16(a3[m], bh[j], acc[4 + m][j], 0, 0, 0);
      }
    __builtin_amdgcn_s_setprio(0);
    BARX();
  }

#pragma unroll
  for (int j = 0; j < 4; ++j) {
    const int col = bn + wcn * 64 + j * 16 + l16;
#pragma unroll
    for (int i = 0; i < 8; ++i) {
      const int row0 = bm + wr * 128 + i * 16 + q * 4;
#pragma unroll
      for (int r = 0; r < 4; ++r)
        C[(size_t)(row0 + r) * TT + col] = acc[i][j][r];
    }
  }
}

extern "C" void kernel_launch(void* const* d_in, const int* in_sizes, int n_in,
                              void* d_out, int out_size, void* d_ws, size_t ws_size,
                              hipStream_t stream)
{
  const int*   inputs     = (const int*)d_in[0];
  const int*   targets    = (const int*)d_in[1];
  const float* input_emb  = (const float*)d_in[2];
  const float* target_emb = (const float*)d_in[3];
  const float* conv_w     = (const float*)d_in[4];
  const float* conv_b     = (const float*)d_in[5];
  const float* dense_w    = (const float*)d_in[6];
  const float* dense_b    = (const float*)d_in[7];
  float* out = (float*)d_out;

  const long long SE = (long long)TT * HID;     // elems per batch (te/ie)
  const size_t SZ = (size_t)NB * SE * 2;        // 16,777,216 B bf16 region

  // workspace map (167,772,160 B total, proven capacity):
  // [0,SZ)        te_hi          -> ieT after logits
  // [SZ,..)       te_lo          -> attn padded (NB*PR+1 rows = 16,787,456 B)
  // [2SZ,3SZ)     ie_hi          -> convwb @ 2SZ+16K (25.2 MB, spans ie_lo)
  // [3SZ,4SZ)     ie_lo
  // [4SZ,4SZ+67M) logit fp32     -> hb bf16 after softmax
  // [4SZ+67M,end) Wbf bf16       -> densewb after attn GEMM
  char* base = (char*)d_ws;
  unsigned short* te_hi = (unsigned short*)(base);
  unsigned short* te_lo = (unsigned short*)(base + SZ);
  unsigned short* ie_hi = (unsigned short*)(base + 2 * SZ);
  unsigned short* ie_lo = (unsigned short*)(base + 3 * SZ);
  float*          logit = (float*)         (base + 4 * SZ);
  unsigned short* Wbf   = (unsigned short*)(base + 4 * SZ + (size_t)NB * TT * TT * 4);
  unsigned short* ieT     = (unsigned short*)(base);
  unsigned short* attnP   = (unsigned short*)(base + SZ);              // padded buffer base
  unsigned short* attnD   = attnP + (size_t)HID;                       // first data row
  unsigned short* convwb  = (unsigned short*)(base + 2 * SZ + 16384);
  unsigned short* hb      = (unsigned short*)(base + 4 * SZ);
  unsigned short* densewb = (unsigned short*)Wbf;

  // 1) gathers: te raw, ie scaled by sqrt(H)=32  (logits = te_raw . ie_scaled)
  gather_split_k<<<NB * TT, 256, 0, stream>>>(targets, target_emb, te_hi, te_lo, 1.0f);
  gather_split_k<<<NB * TT, 256, 0, stream>>>(inputs,  input_emb,  ie_hi, ie_lo, 32.0f);

  // 2) fused hi/lo logits (256² 4-phase deep)
  gemm_logits256_k<<<dim3(TT / 256, TT / 256, NB), 512, 0, stream>>>(
      te_hi, te_lo, ie_hi, ie_lo, logit);

  // 3) ieT[h][s] = ie_hi[s][h]  (overwrites te_hi, dead)
  transpose_bf_k<unsigned short><<<dim3(HID / 32, TT / 32, NB), 256, 0, stream>>>(
      ie_hi, ieT, TT, HID, SE, SE);

  // 4) softmax -> bf16 W
  softmax_bf_k<<<NB * TT, 256, 0, stream>>>(logit, Wbf);

  // 5) guard rows + attn[t][h] = W[t][s] . ieT[h][s] -> padded bf16 buffer
  zero_guard_k<<<NB + 1, 256, 0, stream>>>(attnP);
  gemm128_k<1, 0><<<dim3(HID / 256, TT / 128, NB), 512, 0, stream>>>(
      Wbf, (long long)TT * TT, TT, ieT, SE, TT,
      attnD, (long long)PR * HID, HID, TT, nullptr);

  // 6) weight transposes (convwb over dead ie region; densewb over dead Wbf)
  transpose_bf_k<float><<<dim3(UD / 32, (3 * HID) / 32, 1), 256, 0, stream>>>(
      conv_w, convwb, 3 * HID, UD, 0, 0);
  transpose_bf_k<float><<<dim3(HID / 32, UD / 32, 1), 256, 0, stream>>>(
      dense_w, densewb, UD, HID, 0, 0);

  // 7) conv: h = relu(b + im2col(attn).convwb^T) -> bf16 (over dead logit)
  gemm256_k<1, 2, 1><<<dim3(UD / 256, TT / 256, NB), 512, 0, stream>>>(
      attnD, (long long)PR * HID, HID, convwb, 0, 3 * HID,
      hb, (long long)TT * UD, UD, 3 * HID, conv_b);

  // 8) dense: out = b + h.densewb^T  (fp32 out)
  gemm128_k<0, 1><<<dim3(HID / 256, TT / 128, NB), 512, 0, stream>>>(
      hb, (long long)TT * UD, UD, densewb, 0, UD,
      out, SE, HID, UD, dense_b);
}